// Round 7
// baseline (121.064 us; speedup 1.0000x reference)
//
#include <hip/hip_runtime.h>
#include <cstdint>

#define D 1024
#define N_TOKENS 4096
#define N_SLOTS 8192
#define NEXP 8
#define NKT 16          // 1024 / BK(=64)
#define MAXT 40         // max 256-row M-tiles: 32 + 7 boundary (+1 margin)
#define TRROWS 4        // W2-transpose tail y-rows (x16 = 64 blocks, 2 jobs each)

typedef float f32x4 __attribute__((ext_vector_type(4)));
typedef __bf16 bf16x8 __attribute__((ext_vector_type(8)));
typedef __attribute__((address_space(3))) uint32_t lds_u32;
typedef __attribute__((address_space(1))) const uint32_t glb_u32;

__device__ __forceinline__ void gload_lds16(const void* g, void* l) {
  __builtin_amdgcn_global_load_lds((glb_u32*)g, (lds_u32*)l, 16, 0, 0);
}

__device__ __forceinline__ ushort f2bf(float f) {
  union { float f; uint32_t u; } c; c.f = f;
  uint32_t u = c.u;
  return (ushort)((u + 0x7FFFu + ((u >> 16) & 1u)) >> 16);
}

__device__ __forceinline__ float bf2f(ushort u) {
  union { uint32_t u; float f; } c; c.u = (uint32_t)u << 16;
  return c.f;
}

__device__ __forceinline__ bf16x8 lds_frag(const ushort* base, int row, int s) {
  return *(const bf16x8*)((const char*)base + row * 128 + ((s ^ (row & 7)) * 16));
}

// TPAD=66: transpose-tile row stride = 132 B = 33 banks (odd) -> 4-way not 16-way.
#define TPAD 66

// ---------------- fused prologue: routing + x-cast + W1/W3 transpose --------
// block 0: routing (256-row tiles now); blocks 1..256: cast x fp32->bf16;
// blocks 257..4352: W1/W3 transpose. W2 transpose lives in gemm1 TAIL blocks
// (runs on the structurally idle CUs of gemm1's final dispatch round).
__global__ void prep_k(const float* __restrict__ x, const int* __restrict__ ei,
                       const float* __restrict__ ew,
                       const float* __restrict__ w1, const float* __restrict__ w3,
                       float* __restrict__ hist_out, int* __restrict__ meta,
                       int* __restrict__ tok, int* __restrict__ smap,
                       ushort* __restrict__ Xbf, ushort* __restrict__ w13t) {
  int bid = blockIdx.x, t = threadIdx.x;
  if (bid == 0) {
    __shared__ int cmat[256][8];   // 8 KB
    __shared__ int off[NEXP + 1];
#pragma unroll
    for (int e = 0; e < NEXP; e++) cmat[t][e] = 0;
    int base = t * 32;
#pragma unroll 4
    for (int j = 0; j < 32; j++) cmat[t][ei[base + j]]++;
    __syncthreads();
    if (t < NEXP) {
      int run = 0;
      for (int i = 0; i < 256; i++) { int v = cmat[i][t]; cmat[i][t] = run; run += v; }
      meta[8 + t] = run;
    }
    __syncthreads();
    if (t == 0) {
      int s = 0;
      for (int e = 0; e < NEXP; e++) { off[e] = s; s += meta[8 + e]; }
      off[NEXP] = s;
      int nt = 0;
      for (int e = 0; e < NEXP; e++)
        for (int r = off[e]; r < off[e + 1]; r += 256)
          if (nt < MAXT) {
            meta[16 + nt] = e;
            meta[96 + nt] = r;
            int re = off[e + 1]; if (r + 256 < re) re = r + 256;
            meta[176 + nt] = re;
            nt++;
          }
      meta[0] = nt;
      for (int e = 0; e < NEXP; e++) hist_out[e] = (float)meta[8 + e];
    }
    __syncthreads();
#pragma unroll 4
    for (int j = 0; j < 32; j++) {
      int slot = base + j;
      int e = ei[slot];
      int p = off[e] + cmat[t][e]++;
      tok[p] = slot >> 1;
      smap[slot] = p;
    }
  } else if (bid <= 256) {
    int cb = bid - 1;
    const float4* xs = (const float4*)x + (size_t)cb * 4096;
    ushort4* xd = (ushort4*)Xbf + (size_t)cb * 4096;
#pragma unroll
    for (int i = 0; i < 16; i++) {
      float4 v = xs[i * 256 + t];
      ushort4 o;
      o.x = f2bf(v.x); o.y = f2bf(v.y); o.z = f2bf(v.z); o.w = f2bf(v.w);
      xd[i * 256 + t] = o;
    }
  } else {
    int wb = bid - 257;
    int z = wb >> 8, rem = wb & 255;
    int kb = rem >> 4, nb = rem & 15;
    int which = z >> 3, e = z & 7;           // which: 0=W1, 1=W3
    const float* src = (which == 0 ? w1 : w3) + (size_t)e * D * D;
    ushort* dst = w13t + (size_t)e * 2048 * D;
    __shared__ ushort tile[64][TPAD];
    int k0 = kb * 64, n0 = nb * 64;
    int r = t >> 4, c = t & 15;
#pragma unroll
    for (int rep = 0; rep < 4; rep++) {
      int krow = rep * 16 + r;
      float4 v = *(const float4*)(src + (size_t)(k0 + krow) * D + n0 + c * 4);
      tile[krow][c * 4 + 0] = f2bf(v.x);
      tile[krow][c * 4 + 1] = f2bf(v.y);
      tile[krow][c * 4 + 2] = f2bf(v.z);
      tile[krow][c * 4 + 3] = f2bf(v.w);
    }
    __syncthreads();
#pragma unroll
    for (int rep = 0; rep < 4; rep++) {
      int lr = rep * 16 + r;
      int nrow = n0 + lr;
      ushort4 o;
      o.x = tile[c * 4 + 0][lr];
      o.y = tile[c * 4 + 1][lr];
      o.z = tile[c * 4 + 2][lr];
      o.w = tile[c * 4 + 3][lr];
      int crow = ((nrow >> 4) << 5) + ((which == 1) ? 16 : 0) + (nrow & 15);
      *(ushort4*)(dst + (size_t)crow * D + k0 + c * 4) = o;
    }
  }
}

// ---- GEMM1: 8-phase/counted-vmcnt grouped GEMM (T3+T4+T5, m248 regime).
// Tile 256(M) x 128(Ni), BK=64, 8 waves (2M x 4N), wave 128x32, 512 thr,
// dbuf LDS 96 KB, 1 block/CU. Staging: 6 gload_lds/thread/K-tile in halves
// of 3; steady state keeps 3 loads in flight across every wait (vmcnt(3),
// never 0 until the final two tiles). Raw s_barrier (no vmcnt(0) drain) +
// sched_barrier(0) pinning. Grid TAIL (y >= MAXT): W2 transpose on the
// idle CUs of the final dispatch round. ----
__global__ __launch_bounds__(512, 2) void gemm1_k(
    const ushort* __restrict__ Xbf, const ushort* __restrict__ W13t,
    ushort* __restrict__ H, const int* __restrict__ tok,
    const int* __restrict__ meta,
    const float* __restrict__ w2, ushort* __restrict__ W2t) {
  __shared__ ushort L[2][24576];   // per buf: A 256x64 (16384) + B 128x64 (8192)
  int tm = blockIdx.y;
  int tid = threadIdx.x;

  if (tm >= MAXT) {
    // ---- W2 transpose tail: 2 independent 256-thread jobs per block,
    // each = R6's 2-deep pipelined 16-tile (e, k-strip) loop ----
    int gid = (tm - MAXT) * 16 + blockIdx.x;           // 0..63
    int half = tid >> 8, t8 = tid & 255;
    int job = gid * 2 + half;                          // 0..127
    int e = job >> 4, kb = job & 15;
    const float* src = w2 + (size_t)e * D * D;
    ushort* dst = W2t + (size_t)e * D * D;
    ushort (*tile)[TPAD] = (ushort(*)[TPAD])(&L[0][0] + half * 4224);
    int r = t8 >> 4, c = t8 & 15;
    int k0 = kb * 64;
    const float* sp = src + (size_t)k0 * D + c * 4;
    float4 va[4], vb[4];
#pragma unroll
    for (int rep = 0; rep < 4; rep++)
      va[rep] = *(const float4*)(sp + (size_t)(rep * 16 + r) * D);
    for (int i = 0; i < 16; i += 2) {
      __syncthreads();
#pragma unroll
      for (int rep = 0; rep < 4; rep++) {
        int krow = rep * 16 + r;
        tile[krow][c * 4 + 0] = f2bf(va[rep].x);
        tile[krow][c * 4 + 1] = f2bf(va[rep].y);
        tile[krow][c * 4 + 2] = f2bf(va[rep].z);
        tile[krow][c * 4 + 3] = f2bf(va[rep].w);
      }
      if (i + 1 < 16)
#pragma unroll
        for (int rep = 0; rep < 4; rep++)
          vb[rep] = *(const float4*)(sp + (size_t)(rep * 16 + r) * D + (i + 1) * 64);
      __syncthreads();
      {
        int n0 = i * 64;
#pragma unroll
        for (int rep = 0; rep < 4; rep++) {
          int lr = rep * 16 + r;
          ushort4 o;
          o.x = tile[c * 4 + 0][lr];
          o.y = tile[c * 4 + 1][lr];
          o.z = tile[c * 4 + 2][lr];
          o.w = tile[c * 4 + 3][lr];
          *(ushort4*)(dst + (size_t)(n0 + lr) * D + k0 + c * 4) = o;
        }
      }
      __syncthreads();
#pragma unroll
      for (int rep = 0; rep < 4; rep++) {
        int krow = rep * 16 + r;
        tile[krow][c * 4 + 0] = f2bf(vb[rep].x);
        tile[krow][c * 4 + 1] = f2bf(vb[rep].y);
        tile[krow][c * 4 + 2] = f2bf(vb[rep].z);
        tile[krow][c * 4 + 3] = f2bf(vb[rep].w);
      }
      if (i + 2 < 16)
#pragma unroll
        for (int rep = 0; rep < 4; rep++)
          va[rep] = *(const float4*)(sp + (size_t)(rep * 16 + r) * D + (i + 2) * 64);
      __syncthreads();
      {
        int n0 = (i + 1) * 64;
#pragma unroll
        for (int rep = 0; rep < 4; rep++) {
          int lr = rep * 16 + r;
          ushort4 o;
          o.x = tile[c * 4 + 0][lr];
          o.y = tile[c * 4 + 1][lr];
          o.z = tile[c * 4 + 2][lr];
          o.w = tile[c * 4 + 3][lr];
          *(ushort4*)(dst + (size_t)(n0 + lr) * D + k0 + c * 4) = o;
        }
      }
    }
    return;
  }
  if (tm >= meta[0]) return;

  int e = meta[16 + tm], r0 = meta[96 + tm], rend = meta[176 + tm];
  int n0i = blockIdx.x * 128;
  int lane = tid & 63, wid = tid >> 6;
  int wm = wid >> 2, wn = wid & 3;

  const char* gX = (const char*)Xbf;
  const char* gB = (const char*)(W13t + (size_t)e * 2048 * D);

  int prow = tid >> 3, pslot = tid & 7;     // 64 rows/group, 8x16B slots/row
  int phys = (pslot ^ (prow & 7)) * 16;     // pre-swizzled source slot
  size_t arow[4];
  int brow[2];
#pragma unroll
  for (int g = 0; g < 4; g++) {
    int gr = r0 + g * 64 + prow; if (gr > N_SLOTS - 1) gr = N_SLOTS - 1;
    arow[g] = (size_t)tok[gr] * 2048;
  }
#pragma unroll
  for (int g = 0; g < 2; g++) brow[g] = n0i + g * 64 + prow;

#define G1A(c, g, kB) gload_lds16(gX + arow[g] + (kB) + phys, \
    (char*)&L[c][0] + ((g) * 512 + tid) * 16)
#define G1B(c, g, kB) gload_lds16(gB + (size_t)brow[g] * 2048 + (kB) + phys, \
    (char*)&L[c][0] + 32768 + ((g) * 512 + tid) * 16)
#define G1H0(c, kB) { G1A(c, 0, kB); G1A(c, 1, kB); G1B(c, 0, kB); }
#define G1H1(c, kB) { G1A(c, 2, kB); G1A(c, 3, kB); G1B(c, 1, kB); }

  f32x4 acc[8][2] = {};

  G1H0(0, 0); G1H1(0, 0);          // tile 0 complete (6 loads)
  G1H0(1, 128);                    // tile 1 half0 (3 loads in flight)
  asm volatile("s_waitcnt vmcnt(3)" ::: "memory");
  __builtin_amdgcn_s_barrier();
  __builtin_amdgcn_sched_barrier(0);

  int cur = 0;
  for (int kt = 0; kt < NKT; kt++) {
    if (kt + 1 < NKT) G1H1(cur ^ 1, (kt + 1) * 128);   // next tile half1
    const ushort* Ab = &L[cur][0];
    const ushort* Bb = &L[cur][16384];
    __builtin_amdgcn_s_setprio(1);
#pragma unroll
    for (int kk = 0; kk < 2; kk++) {
      int s = kk * 4 + (lane >> 4);
      bf16x8 b0 = lds_frag(Bb, wn * 32 + (lane & 15), s);
      bf16x8 b1 = lds_frag(Bb, wn * 32 + 16 + (lane & 15), s);
#pragma unroll
      for (int mf = 0; mf < 8; mf++) {
        bf16x8 a = lds_frag(Ab, wm * 128 + mf * 16 + (lane & 15), s);
        acc[mf][0] = __builtin_amdgcn_mfma_f32_16x16x32_bf16(a, b0, acc[mf][0], 0, 0, 0);
        acc[mf][1] = __builtin_amdgcn_mfma_f32_16x16x32_bf16(a, b1, acc[mf][1], 0, 0, 0);
      }
    }
    __builtin_amdgcn_s_setprio(0);
    __builtin_amdgcn_s_barrier();        // all waves done reading buf[cur]
    __builtin_amdgcn_sched_barrier(0);
    if (kt + 2 < NKT) {
      G1H0(cur, (kt + 2) * 128);         // tile kt+2 half0 -> buf[cur] (now free)
      asm volatile("s_waitcnt vmcnt(3)" ::: "memory");  // tile kt+1 landed; 3 in flight
    } else {
      asm volatile("s_waitcnt vmcnt(0)" ::: "memory");
    }
    __builtin_amdgcn_s_barrier();        // buf[cur^1] = tile kt+1 visible to all
    __builtin_amdgcn_sched_barrier(0);
    cur ^= 1;
  }

  // epilogue: (W1,W3) pair -> silu(g)*u ; wave covers 16 h-cols
  int cb = (n0i >> 1) + wn * 16 + (lane & 15);
#pragma unroll
  for (int mf = 0; mf < 8; mf++)
#pragma unroll
    for (int v = 0; v < 4; v++) {
      int r = r0 + wm * 128 + mf * 16 + (lane >> 4) * 4 + v;
      if (r >= rend) continue;
      float g = acc[mf][0][v], u = acc[mf][1][v];
      float hv = g / (1.f + __expf(-g)) * u;
      H[(size_t)r * D + cb] = f2bf(hv);
    }
#undef G1A
#undef G1B
#undef G1H0
#undef G1H1
}

// ---- GEMM2: same 8-wave counted-vmcnt pipeline. Tile 256(M) x 256(N),
// BK=64, wave 128x64, dbuf LDS 128 KB, 1 block/CU. 8 loads/thread/K-tile
// in halves of 4; vmcnt(4). Writes RAW per-slot rows Y (bf16). ----
__global__ __launch_bounds__(512, 2) void gemm2_k(
    const ushort* __restrict__ Hm, const ushort* __restrict__ W2t,
    ushort* __restrict__ Y, const int* __restrict__ meta) {
  __shared__ ushort L[2][32768];   // per buf: A 256x64 + B 256x64
  int tm = blockIdx.y;
  if (tm >= meta[0]) return;
  int e = meta[16 + tm], r0 = meta[96 + tm], rend = meta[176 + tm];
  int n0 = blockIdx.x * 256;
  int tid = threadIdx.x, lane = tid & 63, wid = tid >> 6;
  int wm = wid >> 2, wn = wid & 3;

  const char* gH = (const char*)Hm;
  const char* gB = (const char*)(W2t + (size_t)e * D * D);

  int prow = tid >> 3, pslot = tid & 7;
  int phys = (pslot ^ (prow & 7)) * 16;
  size_t arow[4];
  int brow[4];
#pragma unroll
  for (int g = 0; g < 4; g++) {
    int gr = r0 + g * 64 + prow; if (gr > N_SLOTS - 1) gr = N_SLOTS - 1;
    arow[g] = (size_t)gr * 2048;
    brow[g] = n0 + g * 64 + prow;
  }

#define G2A(c, g, kB) gload_lds16(gH + arow[g] + (kB) + phys, \
    (char*)&L[c][0] + ((g) * 512 + tid) * 16)
#define G2B(c, g, kB) gload_lds16(gB + (size_t)brow[g] * 2048 + (kB) + phys, \
    (char*)&L[c][0] + 32768 + ((g) * 512 + tid) * 16)
#define G2H0(c, kB) { G2A(c, 0, kB); G2A(c, 1, kB); G2B(c, 0, kB); G2B(c, 1, kB); }
#define G2H1(c, kB) { G2A(c, 2, kB); G2A(c, 3, kB); G2B(c, 2, kB); G2B(c, 3, kB); }

  f32x4 acc[8][4] = {};

  G2H0(0, 0); G2H1(0, 0);
  G2H0(1, 128);
  asm volatile("s_waitcnt vmcnt(4)" ::: "memory");
  __builtin_amdgcn_s_barrier();
  __builtin_amdgcn_sched_barrier(0);

  int cur = 0;
  for (int kt = 0; kt < NKT; kt++) {
    if (kt + 1 < NKT) G2H1(cur ^ 1, (kt + 1) * 128);
    const ushort* Ab = &L[cur][0];
    const ushort* Bb = &L[cur][16384];
    __builtin_amdgcn_s_setprio(1);
#pragma unroll
    for (int kk = 0; kk < 2; kk++) {
      int s = kk * 4 + (lane >> 4);
      bf16x8 b[4];
#pragma unroll
      for (int nf = 0; nf < 4; nf++)
        b[nf] = lds_frag(Bb, wn * 64 + nf * 16 + (lane & 15), s);
#pragma unroll
      for (int mf = 0; mf < 8; mf++) {
        bf16x8 a = lds_frag(Ab, wm * 128 + mf * 16 + (lane & 15), s);
#pragma unroll
        for (int nf = 0; nf < 4; nf++)
          acc[mf][nf] = __builtin_amdgcn_mfma_f32_16x16x32_bf16(a, b[nf], acc[mf][nf], 0, 0, 0);
      }
    }
    __builtin_amdgcn_s_setprio(0);
    __builtin_amdgcn_s_barrier();
    __builtin_amdgcn_sched_barrier(0);
    if (kt + 2 < NKT) {
      G2H0(cur, (kt + 2) * 128);
      asm volatile("s_waitcnt vmcnt(4)" ::: "memory");
    } else {
      asm volatile("s_waitcnt vmcnt(0)" ::: "memory");
    }
    __builtin_amdgcn_s_barrier();
    __builtin_amdgcn_sched_barrier(0);
    cur ^= 1;
  }

#pragma unroll
  for (int mf = 0; mf < 8; mf++)
#pragma unroll
    for (int v = 0; v < 4; v++) {
      int r = r0 + wm * 128 + mf * 16 + (lane >> 4) * 4 + v;
      if (r >= rend) continue;
#pragma unroll
      for (int nf = 0; nf < 4; nf++)
        Y[(size_t)r * D + n0 + wn * 64 + nf * 16 + (lane & 15)] = f2bf(acc[mf][nf][v]);
    }
#undef G2A
#undef G2B
#undef G2H0
#undef G2H1
}

// ---- combine: out[t] = ew[2t]*Y[smap[2t]] + ew[2t+1]*Y[smap[2t+1]] ----
__global__ void combine_k(const ushort* __restrict__ Y, const int* __restrict__ smap,
                          const float* __restrict__ ew, float* __restrict__ out) {
  int tkn = blockIdx.x * 4 + (threadIdx.x >> 6);
  int lane = threadIdx.x & 63;
  int p0 = smap[2 * tkn], p1 = smap[2 * tkn + 1];
  float w0 = ew[2 * tkn], w1 = ew[2 * tkn + 1];
  const ushort4* y0 = (const ushort4*)(Y + (size_t)p0 * D);
  const ushort4* y1 = (const ushort4*)(Y + (size_t)p1 * D);
  float4* o = (float4*)(out + (size_t)tkn * D);
#pragma unroll
  for (int j = 0; j < 4; j++) {
    int c = j * 64 + lane;
    ushort4 a = y0[c], b = y1[c];
    float4 v;
    v.x = w0 * bf2f(a.x) + w1 * bf2f(b.x);
    v.y = w0 * bf2f(a.y) + w1 * bf2f(b.y);
    v.z = w0 * bf2f(a.z) + w1 * bf2f(b.z);
    v.w = w0 * bf2f(a.w) + w1 * bf2f(b.w);
    o[c] = v;
  }
}

extern "C" void kernel_launch(void* const* d_in, const int* in_sizes, int n_in,
                              void* d_out, int out_size, void* d_ws, size_t ws_size,
                              hipStream_t stream) {
  const float* x  = (const float*)d_in[0];
  const float* ew = (const float*)d_in[1];
  const int*   ei = (const int*)d_in[2];
  const float* w1 = (const float*)d_in[3];
  const float* w3 = (const float*)d_in[4];
  const float* w2 = (const float*)d_in[5];
  float* out = (float*)d_out;

  char* ws = (char*)d_ws;
  int*    meta = (int*)ws;                            // 4 KB
  int*    tok  = (int*)(ws + 4096);                   // 32 KB
  int*    smap = (int*)(ws + 4096 + 32768);           // 32 KB
  ushort* Xbf  = (ushort*)(ws + (1ull << 20));        // [1,9) MB (token order)
  ushort* W13t = (ushort*)(ws + (9ull << 20));        // [9,41) MB (interleaved)
  ushort* W2t  = (ushort*)(ws + (41ull << 20));       // [41,57) MB (by gemm1 tail)
  ushort* Hm   = (ushort*)(ws + (57ull << 20));       // [57,73) MB (slot order)
  // Y overlays Xbf + W13t head: both dead once gemm1 completes (stream order)
  ushort* Ym   = (ushort*)(ws + (1ull << 20));        // [1,17) MB

  prep_k<<<4353, 256, 0, stream>>>(x, ei, ew, w1, w3,
                                   out + (size_t)N_TOKENS * D, meta, tok, smap,
                                   Xbf, W13t);
  gemm1_k<<<dim3(16, MAXT + TRROWS), 512, 0, stream>>>(Xbf, W13t, Hm, tok, meta, w2, W2t);
  gemm2_k<<<dim3(4, MAXT), 512, 0, stream>>>(Hm, W2t, Ym, meta);
  combine_k<<<N_TOKENS / 4, 256, 0, stream>>>(Ym, smap, ew, out);
}

// Round 8
// 114.535 us; speedup vs baseline: 1.0570x; 1.0570x over previous
//
#include <hip/hip_runtime.h>
#include <cstdint>

#define D 1024
#define N_TOKENS 4096
#define N_SLOTS 8192
#define NEXP 8
#define NKT 16          // 1024 / BK(=64)
#define MAXT 80         // max 128-row tiles: 64 + 7 boundary
#define NTRF 8          // W2-transpose front y-rows (x16 = 128 blocks x 16 tiles)

typedef float f32x4 __attribute__((ext_vector_type(4)));
typedef __bf16 bf16x8 __attribute__((ext_vector_type(8)));
typedef __attribute__((address_space(3))) uint32_t lds_u32;
typedef __attribute__((address_space(1))) const uint32_t glb_u32;

__device__ __forceinline__ void gload_lds16(const void* g, void* l) {
  __builtin_amdgcn_global_load_lds((glb_u32*)g, (lds_u32*)l, 16, 0, 0);
}

__device__ __forceinline__ ushort f2bf(float f) {
  union { float f; uint32_t u; } c; c.f = f;
  uint32_t u = c.u;
  return (ushort)((u + 0x7FFFu + ((u >> 16) & 1u)) >> 16);
}

__device__ __forceinline__ float bf2f(ushort u) {
  union { uint32_t u; float f; } c; c.u = (uint32_t)u << 16;
  return c.f;
}

__device__ __forceinline__ bf16x8 lds_frag(const ushort* base, int row, int s) {
  return *(const bf16x8*)((const char*)base + row * 128 + ((s ^ (row & 7)) * 16));
}

// TPAD=66: transpose-tile row stride = 132 B = 33 banks (odd) -> 4-way not 16-way.
#define TPAD 66

// ---------------- fused prologue: routing + x-cast + W1/W3 transpose --------
// block 0: routing; blocks 1..256: cast x fp32->bf16 (token order);
// blocks 257..4352: W1/W3 transpose (fp32 [e][k][n] -> bf16 [e][n'][k] interleave)
// W2 transpose lives in gemm1 FRONT blocks (128 pipelined blocks).
__global__ void prep_k(const float* __restrict__ x, const int* __restrict__ ei,
                       const float* __restrict__ ew,
                       const float* __restrict__ w1, const float* __restrict__ w3,
                       float* __restrict__ hist_out, int* __restrict__ meta,
                       int* __restrict__ tok, int* __restrict__ smap,
                       ushort* __restrict__ Xbf, ushort* __restrict__ w13t) {
  int bid = blockIdx.x, t = threadIdx.x;
  if (bid == 0) {
    // deterministic routing: per-thread counts over contiguous 32-slot chunks
    __shared__ int cmat[256][8];   // 8 KB
    __shared__ int off[NEXP + 1];
#pragma unroll
    for (int e = 0; e < NEXP; e++) cmat[t][e] = 0;
    int base = t * 32;
#pragma unroll 4
    for (int j = 0; j < 32; j++) cmat[t][ei[base + j]]++;
    __syncthreads();
    if (t < NEXP) {
      int run = 0;
      for (int i = 0; i < 256; i++) { int v = cmat[i][t]; cmat[i][t] = run; run += v; }
      meta[8 + t] = run;
    }
    __syncthreads();
    if (t == 0) {
      int s = 0;
      for (int e = 0; e < NEXP; e++) { off[e] = s; s += meta[8 + e]; }
      off[NEXP] = s;
      int nt = 0;
      for (int e = 0; e < NEXP; e++)
        for (int r = off[e]; r < off[e + 1]; r += 128)
          if (nt < MAXT) {
            meta[16 + nt] = e;
            meta[96 + nt] = r;
            int re = off[e + 1]; if (r + 128 < re) re = r + 128;
            meta[176 + nt] = re;
            nt++;
          }
      meta[0] = nt;
      for (int e = 0; e < NEXP; e++) hist_out[e] = (float)meta[8 + e];
    }
    __syncthreads();
    // deterministic scatter; also record inverse map slot -> position
#pragma unroll 4
    for (int j = 0; j < 32; j++) {
      int slot = base + j;
      int e = ei[slot];
      int p = off[e] + cmat[t][e]++;
      tok[p] = slot >> 1;
      smap[slot] = p;
    }
  } else if (bid <= 256) {
    // cast x -> bf16, token order. 16384 elems per block.
    int cb = bid - 1;
    const float4* xs = (const float4*)x + (size_t)cb * 4096;
    ushort4* xd = (ushort4*)Xbf + (size_t)cb * 4096;
#pragma unroll
    for (int i = 0; i < 16; i++) {
      float4 v = xs[i * 256 + t];
      ushort4 o;
      o.x = f2bf(v.x); o.y = f2bf(v.y); o.z = f2bf(v.z); o.w = f2bf(v.w);
      xd[i * 256 + t] = o;
    }
  } else {
    int wb = bid - 257;
    int z = wb >> 8, rem = wb & 255;
    int kb = rem >> 4, nb = rem & 15;
    int which = z >> 3, e = z & 7;           // which: 0=W1, 1=W3
    const float* src = (which == 0 ? w1 : w3) + (size_t)e * D * D;
    ushort* dst = w13t + (size_t)e * 2048 * D;
    __shared__ ushort tile[64][TPAD];
    int k0 = kb * 64, n0 = nb * 64;
    int r = t >> 4, c = t & 15;
#pragma unroll
    for (int rep = 0; rep < 4; rep++) {
      int krow = rep * 16 + r;
      float4 v = *(const float4*)(src + (size_t)(k0 + krow) * D + n0 + c * 4);
      tile[krow][c * 4 + 0] = f2bf(v.x);
      tile[krow][c * 4 + 1] = f2bf(v.y);
      tile[krow][c * 4 + 2] = f2bf(v.z);
      tile[krow][c * 4 + 3] = f2bf(v.w);
    }
    __syncthreads();
#pragma unroll
    for (int rep = 0; rep < 4; rep++) {
      int lr = rep * 16 + r;
      int nrow = n0 + lr;
      ushort4 o;
      o.x = tile[c * 4 + 0][lr];
      o.y = tile[c * 4 + 1][lr];
      o.z = tile[c * 4 + 2][lr];
      o.w = tile[c * 4 + 3][lr];
      int crow = ((nrow >> 4) << 5) + ((which == 1) ? 16 : 0) + (nrow & 15);
      *(ushort4*)(dst + (size_t)crow * D + k0 + c * 4) = o;
    }
  }
}

// ---- GEMM1: tile 128(M) x 128(Ni), BK=64, 4 waves 2x2, wave 64x64,
// single-buffered LDS (32 KB), 4-5 blocks/CU TLP (687 TF = 2ph grouped
// ceiling; R1/R7 proved vmcnt/256-tile variants regress in this geometry).
// T1 XCD-chunked swizzle: HW places linear block id on XCD (id%8); the
// remap work=(flat&7)*chunk + flat>>3 gives each XCD a CONTIGUOUS work
// range (10 whole tiles), so the 16 Ni-blocks sharing an A-panel become
// L2-local instead of scattered over 8 XCD L2s. Bijective: 1280%8==0.
// Grid FRONT (y < NTRF): W2 transpose, 128 blocks x 16 tiles, 2-deep
// pipelined (R6 config). W2t consumed only by gemm2 (stream-ordered). ----
__global__ __launch_bounds__(256, 4) void gemm1_k(
    const ushort* __restrict__ Xbf, const ushort* __restrict__ W13t,
    ushort* __restrict__ H, const int* __restrict__ tok,
    const int* __restrict__ meta,
    const float* __restrict__ w2, ushort* __restrict__ W2t) {
  __shared__ ushort sA[128 * 64];
  __shared__ ushort sB[128 * 64];
  int tm = blockIdx.y;
  int tid = threadIdx.x;

  if (tm < NTRF) {
    // ---- W2 transpose front-path: one (expert, k-strip) per block,
    // 16 n-tiles, 2-deep pipelined ----
    int gid = tm * 16 + blockIdx.x;                    // 0..127
    int e = gid >> 4, kb = gid & 15;
    const float* src = w2 + (size_t)e * D * D;
    ushort* dst = W2t + (size_t)e * D * D;
    ushort (*tile)[TPAD] = (ushort(*)[TPAD])&sA[0];    // 8.25 KB overlay scratch
    int r = tid >> 4, c = tid & 15;
    int k0 = kb * 64;
    const float* sp = src + (size_t)k0 * D + c * 4;    // + krow*D + n0
    float4 va[4], vb[4];
#pragma unroll
    for (int rep = 0; rep < 4; rep++)
      va[rep] = *(const float4*)(sp + (size_t)(rep * 16 + r) * D);   // tile 0
    for (int i = 0; i < 16; i += 2) {
      __syncthreads();                       // prev store-phase reads done
#pragma unroll
      for (int rep = 0; rep < 4; rep++) {    // write tile i (waits va loads)
        int krow = rep * 16 + r;
        tile[krow][c * 4 + 0] = f2bf(va[rep].x);
        tile[krow][c * 4 + 1] = f2bf(va[rep].y);
        tile[krow][c * 4 + 2] = f2bf(va[rep].z);
        tile[krow][c * 4 + 3] = f2bf(va[rep].w);
      }
      if (i + 1 < 16)                        // issue tile i+1 loads (async)
#pragma unroll
        for (int rep = 0; rep < 4; rep++)
          vb[rep] = *(const float4*)(sp + (size_t)(rep * 16 + r) * D + (i + 1) * 64);
      __syncthreads();                       // tile i ready in LDS
      {
        int n0 = i * 64;
#pragma unroll
        for (int rep = 0; rep < 4; rep++) {
          int lr = rep * 16 + r;
          ushort4 o;
          o.x = tile[c * 4 + 0][lr];
          o.y = tile[c * 4 + 1][lr];
          o.z = tile[c * 4 + 2][lr];
          o.w = tile[c * 4 + 3][lr];
          *(ushort4*)(dst + (size_t)(n0 + lr) * D + k0 + c * 4) = o;
        }
      }
      __syncthreads();                       // tile i reads done
#pragma unroll
      for (int rep = 0; rep < 4; rep++) {    // write tile i+1 (waits vb loads)
        int krow = rep * 16 + r;
        tile[krow][c * 4 + 0] = f2bf(vb[rep].x);
        tile[krow][c * 4 + 1] = f2bf(vb[rep].y);
        tile[krow][c * 4 + 2] = f2bf(vb[rep].z);
        tile[krow][c * 4 + 3] = f2bf(vb[rep].w);
      }
      if (i + 2 < 16)                        // issue tile i+2 loads (async)
#pragma unroll
        for (int rep = 0; rep < 4; rep++)
          va[rep] = *(const float4*)(sp + (size_t)(rep * 16 + r) * D + (i + 2) * 64);
      __syncthreads();                       // tile i+1 ready in LDS
      {
        int n0 = (i + 1) * 64;
#pragma unroll
        for (int rep = 0; rep < 4; rep++) {
          int lr = rep * 16 + r;
          ushort4 o;
          o.x = tile[c * 4 + 0][lr];
          o.y = tile[c * 4 + 1][lr];
          o.z = tile[c * 4 + 2][lr];
          o.w = tile[c * 4 + 3][lr];
          *(ushort4*)(dst + (size_t)(n0 + lr) * D + k0 + c * 4) = o;
        }
      }
    }
    return;
  }
  // ---- T1 XCD-chunked remap of the main-GEMM work space (1280 works) ----
  {
    int flat = (tm - NTRF) * 16 + blockIdx.x;    // 0..1279; HW XCD ~ flat&7
    int work = (flat & 7) * 160 + (flat >> 3);   // XCD c owns works [c*160,(c+1)*160)
    tm = work >> 4;                              // tile index
    blockIdx_x_remap:;
    int wnb = work & 15;                         // Ni-block
    if (tm >= meta[0]) return;

    int e = meta[16 + tm], r0 = meta[96 + tm], rend = meta[176 + tm];
    int n0i = wnb * 128;
    int lane = tid & 63, wid = tid >> 6;
    int wm = wid >> 1, wn = wid & 1;

    const char* gX = (const char*)Xbf;
    const char* gB = (const char*)(W13t + (size_t)e * 2048 * D);

    int prow = tid >> 3, pslot = tid & 7;
    size_t arow[4];
    int brow[4], phys[4];
#pragma unroll
    for (int i = 0; i < 4; i++) {
      int row = i * 32 + prow;
      int gr = r0 + row; if (gr > N_SLOTS - 1) gr = N_SLOTS - 1;
      arow[i] = (size_t)tok[gr] * 2048;
      brow[i] = n0i + row;
      phys[i] = (pslot ^ (row & 7)) * 16;
    }

    f32x4 acc[4][4] = {};

    for (int kt = 0; kt < NKT; kt++) {
      int kb = kt * 128;
#pragma unroll
      for (int i = 0; i < 4; i++) {
        gload_lds16(gX + arow[i] + kb + phys[i], (char*)sA + (i * 256 + tid) * 16);
        gload_lds16(gB + (size_t)brow[i] * 2048 + kb + phys[i],
                    (char*)sB + (i * 256 + tid) * 16);
      }
      __syncthreads();   // vmcnt(0) drain + barrier: tile ready
#pragma unroll
      for (int kk = 0; kk < 2; kk++) {
        int s = kk * 4 + (lane >> 4);
        bf16x8 a[4], b[4];
#pragma unroll
        for (int mf = 0; mf < 4; mf++)
          a[mf] = lds_frag(sA, wm * 64 + mf * 16 + (lane & 15), s);
#pragma unroll
        for (int nf = 0; nf < 4; nf++)
          b[nf] = lds_frag(sB, wn * 64 + nf * 16 + (lane & 15), s);
#pragma unroll
        for (int mf = 0; mf < 4; mf++)
#pragma unroll
          for (int nf = 0; nf < 4; nf++)
            acc[mf][nf] = __builtin_amdgcn_mfma_f32_16x16x32_bf16(a[mf], b[nf], acc[mf][nf], 0, 0, 0);
      }
      __syncthreads();   // all reads done; LDS free for next stage
    }

    // epilogue: nf pairs (W1,W3) -> silu(g)*u
    int cb = (n0i >> 1) + wn * 32 + (lane & 15);
#pragma unroll
    for (int mf = 0; mf < 4; mf++)
#pragma unroll
      for (int v = 0; v < 4; v++) {
        int r = r0 + wm * 64 + mf * 16 + (lane >> 4) * 4 + v;
        if (r >= rend) continue;
#pragma unroll
        for (int p = 0; p < 2; p++) {
          float g = acc[mf][2 * p][v], u = acc[mf][2 * p + 1][v];
          float hv = g / (1.f + __expf(-g)) * u;
          H[(size_t)r * D + cb + p * 16] = f2bf(hv);
        }
      }
  }
}

// ---- GEMM2: tile 128(M) x 128(N), BK=64, 4 waves 2x2, wave 64x64,
// single-buffered (32 KB, 4-5 blocks/CU). T1 XCD-chunked remap (640 works,
// 640%8==0, chunk 80). Writes RAW per-slot rows Y. ----
__global__ __launch_bounds__(256, 4) void gemm2_k(
    const ushort* __restrict__ Hm, const ushort* __restrict__ W2t,
    ushort* __restrict__ Y, const int* __restrict__ meta) {
  __shared__ ushort sA[128 * 64];
  __shared__ ushort sB[128 * 64];
  int flat = blockIdx.y * 8 + blockIdx.x;      // 0..639; HW XCD ~ flat&7
  int work = (flat & 7) * 80 + (flat >> 3);    // XCD c owns works [c*80,(c+1)*80)
  int tm = work >> 3, wnb = work & 7;
  if (tm >= meta[0]) return;
  int e = meta[16 + tm], r0 = meta[96 + tm], rend = meta[176 + tm];
  int n0 = wnb * 128;
  int tid = threadIdx.x, lane = tid & 63, wid = tid >> 6;
  int wm = wid >> 1, wn = wid & 1;

  const char* gH = (const char*)Hm;
  const char* gB = (const char*)(W2t + (size_t)e * D * D);

  int prow = tid >> 3, pslot = tid & 7;
  size_t arow[4];
  int brow[4], phys[4];
#pragma unroll
  for (int i = 0; i < 4; i++) {
    int row = i * 32 + prow;
    int gr = r0 + row; if (gr > N_SLOTS - 1) gr = N_SLOTS - 1;
    arow[i] = (size_t)gr * 2048;
    brow[i] = n0 + row;
    phys[i] = (pslot ^ (row & 7)) * 16;
  }

  f32x4 acc[4][4] = {};

  for (int kt = 0; kt < NKT; kt++) {
    int kb = kt * 128;
#pragma unroll
    for (int i = 0; i < 4; i++) {
      gload_lds16(gH + arow[i] + kb + phys[i], (char*)sA + (i * 256 + tid) * 16);
      gload_lds16(gB + (size_t)brow[i] * 2048 + kb + phys[i],
                  (char*)sB + (i * 256 + tid) * 16);
    }
    __syncthreads();
#pragma unroll
    for (int kk = 0; kk < 2; kk++) {
      int s = kk * 4 + (lane >> 4);
      bf16x8 a[4], b[4];
#pragma unroll
      for (int mf = 0; mf < 4; mf++)
        a[mf] = lds_frag(sA, wm * 64 + mf * 16 + (lane & 15), s);
#pragma unroll
      for (int nf = 0; nf < 4; nf++)
        b[nf] = lds_frag(sB, wn * 64 + nf * 16 + (lane & 15), s);
#pragma unroll
      for (int mf = 0; mf < 4; mf++)
#pragma unroll
        for (int nf = 0; nf < 4; nf++)
          acc[mf][nf] = __builtin_amdgcn_mfma_f32_16x16x32_bf16(a[mf], b[nf], acc[mf][nf], 0, 0, 0);
    }
    __syncthreads();
  }

#pragma unroll
  for (int mf = 0; mf < 4; mf++)
#pragma unroll
    for (int v = 0; v < 4; v++) {
      int r = r0 + wm * 64 + mf * 16 + (lane >> 4) * 4 + v;
      if (r >= rend) continue;
#pragma unroll
      for (int nf = 0; nf < 4; nf++)
        Y[(size_t)r * D + n0 + wn * 64 + nf * 16 + (lane & 15)] = f2bf(acc[mf][nf][v]);
    }
}

// ---- combine: out[t] = ew[2t]*Y[smap[2t]] + ew[2t+1]*Y[smap[2t+1]] ----
__global__ void combine_k(const ushort* __restrict__ Y, const int* __restrict__ smap,
                          const float* __restrict__ ew, float* __restrict__ out) {
  int tkn = blockIdx.x * 4 + (threadIdx.x >> 6);
  int lane = threadIdx.x & 63;
  int p0 = smap[2 * tkn], p1 = smap[2 * tkn + 1];
  float w0 = ew[2 * tkn], w1 = ew[2 * tkn + 1];
  const ushort4* y0 = (const ushort4*)(Y + (size_t)p0 * D);
  const ushort4* y1 = (const ushort4*)(Y + (size_t)p1 * D);
  float4* o = (float4*)(out + (size_t)tkn * D);
#pragma unroll
  for (int j = 0; j < 4; j++) {
    int c = j * 64 + lane;
    ushort4 a = y0[c], b = y1[c];
    float4 v;
    v.x = w0 * bf2f(a.x) + w1 * bf2f(b.x);
    v.y = w0 * bf2f(a.y) + w1 * bf2f(b.y);
    v.z = w0 * bf2f(a.z) + w1 * bf2f(b.z);
    v.w = w0 * bf2f(a.w) + w1 * bf2f(b.w);
    o[c] = v;
  }
}

extern "C" void kernel_launch(void* const* d_in, const int* in_sizes, int n_in,
                              void* d_out, int out_size, void* d_ws, size_t ws_size,
                              hipStream_t stream) {
  const float* x  = (const float*)d_in[0];
  const float* ew = (const float*)d_in[1];
  const int*   ei = (const int*)d_in[2];
  const float* w1 = (const float*)d_in[3];
  const float* w3 = (const float*)d_in[4];
  const float* w2 = (const float*)d_in[5];
  float* out = (float*)d_out;

  char* ws = (char*)d_ws;
  int*    meta = (int*)ws;                            // 4 KB
  int*    tok  = (int*)(ws + 4096);                   // 32 KB
  int*    smap = (int*)(ws + 4096 + 32768);           // 32 KB
  ushort* Xbf  = (ushort*)(ws + (1ull << 20));        // [1,9) MB (token order)
  ushort* W13t = (ushort*)(ws + (9ull << 20));        // [9,41) MB (interleaved)
  ushort* W2t  = (ushort*)(ws + (41ull << 20));       // [41,57) MB (by gemm1 front)
  ushort* Hm   = (ushort*)(ws + (57ull << 20));       // [57,73) MB (slot order)
  // Y overlays Xbf + W13t head: both dead once gemm1 completes (stream order)
  ushort* Ym   = (ushort*)(ws + (1ull << 20));        // [1,17) MB

  prep_k<<<4353, 256, 0, stream>>>(x, ei, ew, w1, w3,
                                   out + (size_t)N_TOKENS * D, meta, tok, smap,
                                   Xbf, W13t);
  gemm1_k<<<dim3(16, NTRF + MAXT), 256, 0, stream>>>(Xbf, W13t, Hm, tok, meta, w2, W2t);
  gemm2_k<<<dim3(8, MAXT), 256, 0, stream>>>(Hm, W2t, Ym, meta);
  combine_k<<<N_TOKENS / 4, 256, 0, stream>>>(Ym, smap, ew, out);
}

// Round 9
// 111.612 us; speedup vs baseline: 1.0847x; 1.0262x over previous
//
#include <hip/hip_runtime.h>
#include <cstdint>

#define D 1024
#define N_TOKENS 4096
#define N_SLOTS 8192
#define NEXP 8
#define NKT 16          // 1024 / BK(=64)
#define MAXT 80         // max 128-row tiles: 64 + 7 boundary
#define NTRF 8          // W2-transpose front y-rows (x16 = 128 blocks x 16 tiles)

typedef float f32x4 __attribute__((ext_vector_type(4)));
typedef __bf16 bf16x8 __attribute__((ext_vector_type(8)));
typedef __attribute__((address_space(3))) uint32_t lds_u32;
typedef __attribute__((address_space(1))) const uint32_t glb_u32;

__device__ __forceinline__ void gload_lds16(const void* g, void* l) {
  __builtin_amdgcn_global_load_lds((glb_u32*)g, (lds_u32*)l, 16, 0, 0);
}

__device__ __forceinline__ ushort f2bf(float f) {
  union { float f; uint32_t u; } c; c.f = f;
  uint32_t u = c.u;
  return (ushort)((u + 0x7FFFu + ((u >> 16) & 1u)) >> 16);
}

__device__ __forceinline__ float bf2f(ushort u) {
  union { uint32_t u; float f; } c; c.u = (uint32_t)u << 16;
  return c.f;
}

__device__ __forceinline__ bf16x8 lds_frag(const ushort* base, int row, int s) {
  return *(const bf16x8*)((const char*)base + row * 128 + ((s ^ (row & 7)) * 16));
}

// TPAD=66: transpose-tile row stride = 132 B = 33 banks (odd) -> 4-way not 16-way.
#define TPAD 66

// ---------------- fused prologue: routing + x-cast + W1/W3 transpose --------
// block 0: routing; blocks 1..256: cast x fp32->bf16 (token order);
// blocks 257..4352: W1/W3 transpose (fp32 [e][k][n] -> bf16 [e][n'][k] interleave)
// W2 transpose lives in gemm1 FRONT blocks (128 pipelined blocks).
__global__ void prep_k(const float* __restrict__ x, const int* __restrict__ ei,
                       const float* __restrict__ ew,
                       const float* __restrict__ w1, const float* __restrict__ w3,
                       float* __restrict__ hist_out, int* __restrict__ meta,
                       int* __restrict__ tok, int* __restrict__ smap,
                       ushort* __restrict__ Xbf, ushort* __restrict__ w13t) {
  int bid = blockIdx.x, t = threadIdx.x;
  if (bid == 0) {
    // deterministic routing: per-thread counts over contiguous 32-slot chunks
    __shared__ int cmat[256][8];   // 8 KB
    __shared__ int off[NEXP + 1];
#pragma unroll
    for (int e = 0; e < NEXP; e++) cmat[t][e] = 0;
    int base = t * 32;
#pragma unroll 4
    for (int j = 0; j < 32; j++) cmat[t][ei[base + j]]++;
    __syncthreads();
    if (t < NEXP) {
      int run = 0;
      for (int i = 0; i < 256; i++) { int v = cmat[i][t]; cmat[i][t] = run; run += v; }
      meta[8 + t] = run;
    }
    __syncthreads();
    if (t == 0) {
      int s = 0;
      for (int e = 0; e < NEXP; e++) { off[e] = s; s += meta[8 + e]; }
      off[NEXP] = s;
      int nt = 0;
      for (int e = 0; e < NEXP; e++)
        for (int r = off[e]; r < off[e + 1]; r += 128)
          if (nt < MAXT) {
            meta[16 + nt] = e;
            meta[96 + nt] = r;
            int re = off[e + 1]; if (r + 128 < re) re = r + 128;
            meta[176 + nt] = re;
            nt++;
          }
      meta[0] = nt;
      for (int e = 0; e < NEXP; e++) hist_out[e] = (float)meta[8 + e];
    }
    __syncthreads();
    // deterministic scatter; also record inverse map slot -> position
#pragma unroll 4
    for (int j = 0; j < 32; j++) {
      int slot = base + j;
      int e = ei[slot];
      int p = off[e] + cmat[t][e]++;
      tok[p] = slot >> 1;
      smap[slot] = p;
    }
  } else if (bid <= 256) {
    // cast x -> bf16, token order. 16384 elems per block.
    int cb = bid - 1;
    const float4* xs = (const float4*)x + (size_t)cb * 4096;
    ushort4* xd = (ushort4*)Xbf + (size_t)cb * 4096;
#pragma unroll
    for (int i = 0; i < 16; i++) {
      float4 v = xs[i * 256 + t];
      ushort4 o;
      o.x = f2bf(v.x); o.y = f2bf(v.y); o.z = f2bf(v.z); o.w = f2bf(v.w);
      xd[i * 256 + t] = o;
    }
  } else {
    int wb = bid - 257;
    int z = wb >> 8, rem = wb & 255;
    int kb = rem >> 4, nb = rem & 15;
    int which = z >> 3, e = z & 7;           // which: 0=W1, 1=W3
    const float* src = (which == 0 ? w1 : w3) + (size_t)e * D * D;
    ushort* dst = w13t + (size_t)e * 2048 * D;
    __shared__ ushort tile[64][TPAD];
    int k0 = kb * 64, n0 = nb * 64;
    int r = t >> 4, c = t & 15;
#pragma unroll
    for (int rep = 0; rep < 4; rep++) {
      int krow = rep * 16 + r;
      float4 v = *(const float4*)(src + (size_t)(k0 + krow) * D + n0 + c * 4);
      tile[krow][c * 4 + 0] = f2bf(v.x);
      tile[krow][c * 4 + 1] = f2bf(v.y);
      tile[krow][c * 4 + 2] = f2bf(v.z);
      tile[krow][c * 4 + 3] = f2bf(v.w);
    }
    __syncthreads();
#pragma unroll
    for (int rep = 0; rep < 4; rep++) {
      int lr = rep * 16 + r;
      int nrow = n0 + lr;
      ushort4 o;
      o.x = tile[c * 4 + 0][lr];
      o.y = tile[c * 4 + 1][lr];
      o.z = tile[c * 4 + 2][lr];
      o.w = tile[c * 4 + 3][lr];
      int crow = ((nrow >> 4) << 5) + ((which == 1) ? 16 : 0) + (nrow & 15);
      *(ushort4*)(dst + (size_t)crow * D + k0 + c * 4) = o;
    }
  }
}

// ---- GEMM1: tile 128(M) x 128(Ni), BK=64, 4 waves 2x2, wave 64x64,
// single-buffered LDS (32 KB), 4-5 blocks/CU TLP (687 TF = 2ph grouped
// ceiling). DIRECT x-fastest mapping (R6): R8's T1 remap cut FETCH 95->82MB
// but REGRESSED 56.7->62.0 us — per-XCD concurrency spanned the whole
// 160-work chunk (10 A-panels live at once) vs x-fastest's 2-3. L2-locality
// gain < temporal-locality loss; T1 stays OFF here (kept on gemm2, where it
// measured -6 us: expert-major chunks make W2t panels L2-resident).
// Grid FRONT (y < NTRF): W2 transpose, 128 blocks x 16 tiles, 2-deep
// pipelined (R6 config). W2t consumed only by gemm2 (stream-ordered). ----
__global__ __launch_bounds__(256, 4) void gemm1_k(
    const ushort* __restrict__ Xbf, const ushort* __restrict__ W13t,
    ushort* __restrict__ H, const int* __restrict__ tok,
    const int* __restrict__ meta,
    const float* __restrict__ w2, ushort* __restrict__ W2t) {
  __shared__ ushort sA[128 * 64];
  __shared__ ushort sB[128 * 64];
  int tm = blockIdx.y;
  int tid = threadIdx.x;

  if (tm < NTRF) {
    // ---- W2 transpose front-path: one (expert, k-strip) per block,
    // 16 n-tiles, 2-deep pipelined ----
    int gid = tm * 16 + blockIdx.x;                    // 0..127
    int e = gid >> 4, kb = gid & 15;
    const float* src = w2 + (size_t)e * D * D;
    ushort* dst = W2t + (size_t)e * D * D;
    ushort (*tile)[TPAD] = (ushort(*)[TPAD])&sA[0];    // 8.25 KB overlay scratch
    int r = tid >> 4, c = tid & 15;
    int k0 = kb * 64;
    const float* sp = src + (size_t)k0 * D + c * 4;    // + krow*D + n0
    float4 va[4], vb[4];
#pragma unroll
    for (int rep = 0; rep < 4; rep++)
      va[rep] = *(const float4*)(sp + (size_t)(rep * 16 + r) * D);   // tile 0
    for (int i = 0; i < 16; i += 2) {
      __syncthreads();                       // prev store-phase reads done
#pragma unroll
      for (int rep = 0; rep < 4; rep++) {    // write tile i (waits va loads)
        int krow = rep * 16 + r;
        tile[krow][c * 4 + 0] = f2bf(va[rep].x);
        tile[krow][c * 4 + 1] = f2bf(va[rep].y);
        tile[krow][c * 4 + 2] = f2bf(va[rep].z);
        tile[krow][c * 4 + 3] = f2bf(va[rep].w);
      }
      if (i + 1 < 16)                        // issue tile i+1 loads (async)
#pragma unroll
        for (int rep = 0; rep < 4; rep++)
          vb[rep] = *(const float4*)(sp + (size_t)(rep * 16 + r) * D + (i + 1) * 64);
      __syncthreads();                       // tile i ready in LDS
      {
        int n0 = i * 64;
#pragma unroll
        for (int rep = 0; rep < 4; rep++) {
          int lr = rep * 16 + r;
          ushort4 o;
          o.x = tile[c * 4 + 0][lr];
          o.y = tile[c * 4 + 1][lr];
          o.z = tile[c * 4 + 2][lr];
          o.w = tile[c * 4 + 3][lr];
          *(ushort4*)(dst + (size_t)(n0 + lr) * D + k0 + c * 4) = o;
        }
      }
      __syncthreads();                       // tile i reads done
#pragma unroll
      for (int rep = 0; rep < 4; rep++) {    // write tile i+1 (waits vb loads)
        int krow = rep * 16 + r;
        tile[krow][c * 4 + 0] = f2bf(vb[rep].x);
        tile[krow][c * 4 + 1] = f2bf(vb[rep].y);
        tile[krow][c * 4 + 2] = f2bf(vb[rep].z);
        tile[krow][c * 4 + 3] = f2bf(vb[rep].w);
      }
      if (i + 2 < 16)                        // issue tile i+2 loads (async)
#pragma unroll
        for (int rep = 0; rep < 4; rep++)
          va[rep] = *(const float4*)(sp + (size_t)(rep * 16 + r) * D + (i + 2) * 64);
      __syncthreads();                       // tile i+1 ready in LDS
      {
        int n0 = (i + 1) * 64;
#pragma unroll
        for (int rep = 0; rep < 4; rep++) {
          int lr = rep * 16 + r;
          ushort4 o;
          o.x = tile[c * 4 + 0][lr];
          o.y = tile[c * 4 + 1][lr];
          o.z = tile[c * 4 + 2][lr];
          o.w = tile[c * 4 + 3][lr];
          *(ushort4*)(dst + (size_t)(n0 + lr) * D + k0 + c * 4) = o;
        }
      }
    }
    return;
  }
  tm -= NTRF;
  if (tm >= meta[0]) return;

  int e = meta[16 + tm], r0 = meta[96 + tm], rend = meta[176 + tm];
  int n0i = blockIdx.x * 128;
  int lane = tid & 63, wid = tid >> 6;
  int wm = wid >> 1, wn = wid & 1;

  const char* gX = (const char*)Xbf;
  const char* gB = (const char*)(W13t + (size_t)e * 2048 * D);

  int prow = tid >> 3, pslot = tid & 7;
  size_t arow[4];
  int brow[4], phys[4];
#pragma unroll
  for (int i = 0; i < 4; i++) {
    int row = i * 32 + prow;
    int gr = r0 + row; if (gr > N_SLOTS - 1) gr = N_SLOTS - 1;
    arow[i] = (size_t)tok[gr] * 2048;
    brow[i] = n0i + row;
    phys[i] = (pslot ^ (row & 7)) * 16;
  }

  f32x4 acc[4][4] = {};

  for (int kt = 0; kt < NKT; kt++) {
    int kb = kt * 128;
#pragma unroll
    for (int i = 0; i < 4; i++) {
      gload_lds16(gX + arow[i] + kb + phys[i], (char*)sA + (i * 256 + tid) * 16);
      gload_lds16(gB + (size_t)brow[i] * 2048 + kb + phys[i],
                  (char*)sB + (i * 256 + tid) * 16);
    }
    __syncthreads();   // vmcnt(0) drain + barrier: tile ready
#pragma unroll
    for (int kk = 0; kk < 2; kk++) {
      int s = kk * 4 + (lane >> 4);
      bf16x8 a[4], b[4];
#pragma unroll
      for (int mf = 0; mf < 4; mf++)
        a[mf] = lds_frag(sA, wm * 64 + mf * 16 + (lane & 15), s);
#pragma unroll
      for (int nf = 0; nf < 4; nf++)
        b[nf] = lds_frag(sB, wn * 64 + nf * 16 + (lane & 15), s);
#pragma unroll
      for (int mf = 0; mf < 4; mf++)
#pragma unroll
        for (int nf = 0; nf < 4; nf++)
          acc[mf][nf] = __builtin_amdgcn_mfma_f32_16x16x32_bf16(a[mf], b[nf], acc[mf][nf], 0, 0, 0);
    }
    __syncthreads();   // all reads done; LDS free for next stage
  }

  // epilogue: nf pairs (W1,W3) -> silu(g)*u
  int cb = (n0i >> 1) + wn * 32 + (lane & 15);
#pragma unroll
  for (int mf = 0; mf < 4; mf++)
#pragma unroll
    for (int v = 0; v < 4; v++) {
      int r = r0 + wm * 64 + mf * 16 + (lane >> 4) * 4 + v;
      if (r >= rend) continue;
#pragma unroll
      for (int p = 0; p < 2; p++) {
        float g = acc[mf][2 * p][v], u = acc[mf][2 * p + 1][v];
        float hv = g / (1.f + __expf(-g)) * u;
        H[(size_t)r * D + cb + p * 16] = f2bf(hv);
      }
    }
}

// ---- GEMM2: tile 128(M) x 128(N), BK=64, 4 waves 2x2, wave 64x64,
// single-buffered (32 KB, 4-5 blocks/CU). T1 XCD-chunked remap (640 works,
// 640%8==0, chunk 80): expert-major chunks keep each XCD's W2t panels
// L2-resident (measured ~-6 us in R8). Writes RAW per-slot rows Y. ----
__global__ __launch_bounds__(256, 4) void gemm2_k(
    const ushort* __restrict__ Hm, const ushort* __restrict__ W2t,
    ushort* __restrict__ Y, const int* __restrict__ meta) {
  __shared__ ushort sA[128 * 64];
  __shared__ ushort sB[128 * 64];
  int flat = blockIdx.y * 8 + blockIdx.x;      // 0..639; HW XCD ~ flat&7
  int work = (flat & 7) * 80 + (flat >> 3);    // XCD c owns works [c*80,(c+1)*80)
  int tm = work >> 3, wnb = work & 7;
  if (tm >= meta[0]) return;
  int e = meta[16 + tm], r0 = meta[96 + tm], rend = meta[176 + tm];
  int n0 = wnb * 128;
  int tid = threadIdx.x, lane = tid & 63, wid = tid >> 6;
  int wm = wid >> 1, wn = wid & 1;

  const char* gH = (const char*)Hm;
  const char* gB = (const char*)(W2t + (size_t)e * D * D);

  int prow = tid >> 3, pslot = tid & 7;
  size_t arow[4];
  int brow[4], phys[4];
#pragma unroll
  for (int i = 0; i < 4; i++) {
    int row = i * 32 + prow;
    int gr = r0 + row; if (gr > N_SLOTS - 1) gr = N_SLOTS - 1;
    arow[i] = (size_t)gr * 2048;
    brow[i] = n0 + row;
    phys[i] = (pslot ^ (row & 7)) * 16;
  }

  f32x4 acc[4][4] = {};

  for (int kt = 0; kt < NKT; kt++) {
    int kb = kt * 128;
#pragma unroll
    for (int i = 0; i < 4; i++) {
      gload_lds16(gH + arow[i] + kb + phys[i], (char*)sA + (i * 256 + tid) * 16);
      gload_lds16(gB + (size_t)brow[i] * 2048 + kb + phys[i],
                  (char*)sB + (i * 256 + tid) * 16);
    }
    __syncthreads();
#pragma unroll
    for (int kk = 0; kk < 2; kk++) {
      int s = kk * 4 + (lane >> 4);
      bf16x8 a[4], b[4];
#pragma unroll
      for (int mf = 0; mf < 4; mf++)
        a[mf] = lds_frag(sA, wm * 64 + mf * 16 + (lane & 15), s);
#pragma unroll
      for (int nf = 0; nf < 4; nf++)
        b[nf] = lds_frag(sB, wn * 64 + nf * 16 + (lane & 15), s);
#pragma unroll
      for (int mf = 0; mf < 4; mf++)
#pragma unroll
        for (int nf = 0; nf < 4; nf++)
          acc[mf][nf] = __builtin_amdgcn_mfma_f32_16x16x32_bf16(a[mf], b[nf], acc[mf][nf], 0, 0, 0);
    }
    __syncthreads();
  }

#pragma unroll
  for (int mf = 0; mf < 4; mf++)
#pragma unroll
    for (int v = 0; v < 4; v++) {
      int r = r0 + wm * 64 + mf * 16 + (lane >> 4) * 4 + v;
      if (r >= rend) continue;
#pragma unroll
      for (int nf = 0; nf < 4; nf++)
        Y[(size_t)r * D + n0 + wn * 64 + nf * 16 + (lane & 15)] = f2bf(acc[mf][nf][v]);
    }
}

// ---- combine: out[t] = ew[2t]*Y[smap[2t]] + ew[2t+1]*Y[smap[2t+1]] ----
__global__ void combine_k(const ushort* __restrict__ Y, const int* __restrict__ smap,
                          const float* __restrict__ ew, float* __restrict__ out) {
  int tkn = blockIdx.x * 4 + (threadIdx.x >> 6);
  int lane = threadIdx.x & 63;
  int p0 = smap[2 * tkn], p1 = smap[2 * tkn + 1];
  float w0 = ew[2 * tkn], w1 = ew[2 * tkn + 1];
  const ushort4* y0 = (const ushort4*)(Y + (size_t)p0 * D);
  const ushort4* y1 = (const ushort4*)(Y + (size_t)p1 * D);
  float4* o = (float4*)(out + (size_t)tkn * D);
#pragma unroll
  for (int j = 0; j < 4; j++) {
    int c = j * 64 + lane;
    ushort4 a = y0[c], b = y1[c];
    float4 v;
    v.x = w0 * bf2f(a.x) + w1 * bf2f(b.x);
    v.y = w0 * bf2f(a.y) + w1 * bf2f(b.y);
    v.z = w0 * bf2f(a.z) + w1 * bf2f(b.z);
    v.w = w0 * bf2f(a.w) + w1 * bf2f(b.w);
    o[c] = v;
  }
}

extern "C" void kernel_launch(void* const* d_in, const int* in_sizes, int n_in,
                              void* d_out, int out_size, void* d_ws, size_t ws_size,
                              hipStream_t stream) {
  const float* x  = (const float*)d_in[0];
  const float* ew = (const float*)d_in[1];
  const int*   ei = (const int*)d_in[2];
  const float* w1 = (const float*)d_in[3];
  const float* w3 = (const float*)d_in[4];
  const float* w2 = (const float*)d_in[5];
  float* out = (float*)d_out;

  char* ws = (char*)d_ws;
  int*    meta = (int*)ws;                            // 4 KB
  int*    tok  = (int*)(ws + 4096);                   // 32 KB
  int*    smap = (int*)(ws + 4096 + 32768);           // 32 KB
  ushort* Xbf  = (ushort*)(ws + (1ull << 20));        // [1,9) MB (token order)
  ushort* W13t = (ushort*)(ws + (9ull << 20));        // [9,41) MB (interleaved)
  ushort* W2t  = (ushort*)(ws + (41ull << 20));       // [41,57) MB (by gemm1 front)
  ushort* Hm   = (ushort*)(ws + (57ull << 20));       // [57,73) MB (slot order)
  // Y overlays Xbf + W13t head: both dead once gemm1 completes (stream order)
  ushort* Ym   = (ushort*)(ws + (1ull << 20));        // [1,17) MB

  prep_k<<<4353, 256, 0, stream>>>(x, ei, ew, w1, w3,
                                   out + (size_t)N_TOKENS * D, meta, tok, smap,
                                   Xbf, W13t);
  gemm1_k<<<dim3(16, NTRF + MAXT), 256, 0, stream>>>(Xbf, W13t, Hm, tok, meta, w2, W2t);
  gemm2_k<<<dim3(8, MAXT), 256, 0, stream>>>(Hm, W2t, Ym, meta);
  combine_k<<<N_TOKENS / 4, 256, 0, stream>>>(Ym, smap, ew, out);
}

// Round 12
// 111.166 us; speedup vs baseline: 1.0890x; 1.0040x over previous
//
#include <hip/hip_runtime.h>
#include <cstdint>

#define D 1024
#define N_TOKENS 4096
#define N_SLOTS 8192
#define NEXP 8
#define NKT 16          // 1024 / BK(=64)
#define MAXT 80         // max 128-row tiles: 64 + 7 boundary
#define NTRF 8          // W2-transpose front y-rows (x16 = 128 blocks x 16 tiles)

typedef float f32x4 __attribute__((ext_vector_type(4)));
typedef __bf16 bf16x8 __attribute__((ext_vector_type(8)));
typedef __attribute__((address_space(3))) uint32_t lds_u32;
typedef __attribute__((address_space(1))) const uint32_t glb_u32;

__device__ __forceinline__ void gload_lds16(const void* g, void* l) {
  __builtin_amdgcn_global_load_lds((glb_u32*)g, (lds_u32*)l, 16, 0, 0);
}

__device__ __forceinline__ ushort f2bf(float f) {
  union { float f; uint32_t u; } c; c.f = f;
  uint32_t u = c.u;
  return (ushort)((u + 0x7FFFu + ((u >> 16) & 1u)) >> 16);
}

__device__ __forceinline__ float bf2f(ushort u) {
  union { uint32_t u; float f; } c; c.u = (uint32_t)u << 16;
  return c.f;
}

__device__ __forceinline__ bf16x8 lds_frag(const ushort* base, int row, int s) {
  return *(const bf16x8*)((const char*)base + row * 128 + ((s ^ (row & 7)) * 16));
}

// TPAD=66: transpose-tile row stride = 132 B = 33 banks (odd) -> 4-way not 16-way.
#define TPAD 66

// ---------------- fused prologue: routing + x-cast + W1/W3 transpose --------
// block 0: routing; blocks 1..256: cast x fp32->bf16 (token order);
// blocks 257..4352: W1/W3 transpose (fp32 [e][k][n] -> bf16 [e][n'][k] interleave)
// W2 transpose lives in gemm1 FRONT blocks (128 pipelined blocks).
__global__ void prep_k(const float* __restrict__ x, const int* __restrict__ ei,
                       const float* __restrict__ ew,
                       const float* __restrict__ w1, const float* __restrict__ w3,
                       float* __restrict__ hist_out, int* __restrict__ meta,
                       int* __restrict__ tok, int* __restrict__ smap,
                       ushort* __restrict__ Xbf, ushort* __restrict__ w13t) {
  int bid = blockIdx.x, t = threadIdx.x;
  if (bid == 0) {
    // deterministic routing: per-thread counts over contiguous 32-slot chunks
    __shared__ int cmat[256][8];   // 8 KB
    __shared__ int off[NEXP + 1];
#pragma unroll
    for (int e = 0; e < NEXP; e++) cmat[t][e] = 0;
    int base = t * 32;
#pragma unroll 4
    for (int j = 0; j < 32; j++) cmat[t][ei[base + j]]++;
    __syncthreads();
    if (t < NEXP) {
      int run = 0;
      for (int i = 0; i < 256; i++) { int v = cmat[i][t]; cmat[i][t] = run; run += v; }
      meta[8 + t] = run;
    }
    __syncthreads();
    if (t == 0) {
      int s = 0;
      for (int e = 0; e < NEXP; e++) { off[e] = s; s += meta[8 + e]; }
      off[NEXP] = s;
      int nt = 0;
      for (int e = 0; e < NEXP; e++)
        for (int r = off[e]; r < off[e + 1]; r += 128)
          if (nt < MAXT) {
            meta[16 + nt] = e;
            meta[96 + nt] = r;
            int re = off[e + 1]; if (r + 128 < re) re = r + 128;
            meta[176 + nt] = re;
            nt++;
          }
      meta[0] = nt;
      for (int e = 0; e < NEXP; e++) hist_out[e] = (float)meta[8 + e];
    }
    __syncthreads();
    // deterministic scatter; also record inverse map slot -> position
#pragma unroll 4
    for (int j = 0; j < 32; j++) {
      int slot = base + j;
      int e = ei[slot];
      int p = off[e] + cmat[t][e]++;
      tok[p] = slot >> 1;
      smap[slot] = p;
    }
  } else if (bid <= 256) {
    // cast x -> bf16, token order. 16384 elems per block.
    int cb = bid - 1;
    const float4* xs = (const float4*)x + (size_t)cb * 4096;
    ushort4* xd = (ushort4*)Xbf + (size_t)cb * 4096;
#pragma unroll
    for (int i = 0; i < 16; i++) {
      float4 v = xs[i * 256 + t];
      ushort4 o;
      o.x = f2bf(v.x); o.y = f2bf(v.y); o.z = f2bf(v.z); o.w = f2bf(v.w);
      xd[i * 256 + t] = o;
    }
  } else {
    int wb = bid - 257;
    int z = wb >> 8, rem = wb & 255;
    int kb = rem >> 4, nb = rem & 15;
    int which = z >> 3, e = z & 7;           // which: 0=W1, 1=W3
    const float* src = (which == 0 ? w1 : w3) + (size_t)e * D * D;
    ushort* dst = w13t + (size_t)e * 2048 * D;
    __shared__ ushort tile[64][TPAD];
    int k0 = kb * 64, n0 = nb * 64;
    int r = t >> 4, c = t & 15;
#pragma unroll
    for (int rep = 0; rep < 4; rep++) {
      int krow = rep * 16 + r;
      float4 v = *(const float4*)(src + (size_t)(k0 + krow) * D + n0 + c * 4);
      tile[krow][c * 4 + 0] = f2bf(v.x);
      tile[krow][c * 4 + 1] = f2bf(v.y);
      tile[krow][c * 4 + 2] = f2bf(v.z);
      tile[krow][c * 4 + 3] = f2bf(v.w);
    }
    __syncthreads();
#pragma unroll
    for (int rep = 0; rep < 4; rep++) {
      int lr = rep * 16 + r;
      int nrow = n0 + lr;
      ushort4 o;
      o.x = tile[c * 4 + 0][lr];
      o.y = tile[c * 4 + 1][lr];
      o.z = tile[c * 4 + 2][lr];
      o.w = tile[c * 4 + 3][lr];
      int crow = ((nrow >> 4) << 5) + ((which == 1) ? 16 : 0) + (nrow & 15);
      *(ushort4*)(dst + (size_t)crow * D + k0 + c * 4) = o;
    }
  }
}

// ---- GEMM1: tile 128(M) x 128(Ni), BK=64, 4 waves 2x2, wave 64x64,
// single-buffered LDS (32 KB), 4-5 blocks/CU TLP (687 TF = 2ph grouped
// ceiling). DIRECT x-fastest mapping (R6): R8's T1 remap cut FETCH 95->82MB
// but REGRESSED 56.7->62.0 us — per-XCD concurrency spanned the whole
// 160-work chunk (10 A-panels live at once) vs x-fastest's 2-3. L2-locality
// gain < temporal-locality loss; T1 stays OFF here (kept on gemm2, where it
// measured -6 us: expert-major chunks make W2t panels L2-resident).
// Grid FRONT (y < NTRF): W2 transpose, 128 blocks x 16 tiles, 2-deep
// pipelined (R6 config). W2t consumed only by gemm2 (stream-ordered). ----
__global__ __launch_bounds__(256, 4) void gemm1_k(
    const ushort* __restrict__ Xbf, const ushort* __restrict__ W13t,
    ushort* __restrict__ H, const int* __restrict__ tok,
    const int* __restrict__ meta,
    const float* __restrict__ w2, ushort* __restrict__ W2t) {
  __shared__ ushort sA[128 * 64];
  __shared__ ushort sB[128 * 64];
  int tm = blockIdx.y;
  int tid = threadIdx.x;

  if (tm < NTRF) {
    // ---- W2 transpose front-path: one (expert, k-strip) per block,
    // 16 n-tiles, 2-deep pipelined ----
    int gid = tm * 16 + blockIdx.x;                    // 0..127
    int e = gid >> 4, kb = gid & 15;
    const float* src = w2 + (size_t)e * D * D;
    ushort* dst = W2t + (size_t)e * D * D;
    ushort (*tile)[TPAD] = (ushort(*)[TPAD])&sA[0];    // 8.25 KB overlay scratch
    int r = tid >> 4, c = tid & 15;
    int k0 = kb * 64;
    const float* sp = src + (size_t)k0 * D + c * 4;    // + krow*D + n0
    float4 va[4], vb[4];
#pragma unroll
    for (int rep = 0; rep < 4; rep++)
      va[rep] = *(const float4*)(sp + (size_t)(rep * 16 + r) * D);   // tile 0
    for (int i = 0; i < 16; i += 2) {
      __syncthreads();                       // prev store-phase reads done
#pragma unroll
      for (int rep = 0; rep < 4; rep++) {    // write tile i (waits va loads)
        int krow = rep * 16 + r;
        tile[krow][c * 4 + 0] = f2bf(va[rep].x);
        tile[krow][c * 4 + 1] = f2bf(va[rep].y);
        tile[krow][c * 4 + 2] = f2bf(va[rep].z);
        tile[krow][c * 4 + 3] = f2bf(va[rep].w);
      }
      if (i + 1 < 16)                        // issue tile i+1 loads (async)
#pragma unroll
        for (int rep = 0; rep < 4; rep++)
          vb[rep] = *(const float4*)(sp + (size_t)(rep * 16 + r) * D + (i + 1) * 64);
      __syncthreads();                       // tile i ready in LDS
      {
        int n0 = i * 64;
#pragma unroll
        for (int rep = 0; rep < 4; rep++) {
          int lr = rep * 16 + r;
          ushort4 o;
          o.x = tile[c * 4 + 0][lr];
          o.y = tile[c * 4 + 1][lr];
          o.z = tile[c * 4 + 2][lr];
          o.w = tile[c * 4 + 3][lr];
          *(ushort4*)(dst + (size_t)(n0 + lr) * D + k0 + c * 4) = o;
        }
      }
      __syncthreads();                       // tile i reads done
#pragma unroll
      for (int rep = 0; rep < 4; rep++) {    // write tile i+1 (waits vb loads)
        int krow = rep * 16 + r;
        tile[krow][c * 4 + 0] = f2bf(vb[rep].x);
        tile[krow][c * 4 + 1] = f2bf(vb[rep].y);
        tile[krow][c * 4 + 2] = f2bf(vb[rep].z);
        tile[krow][c * 4 + 3] = f2bf(vb[rep].w);
      }
      if (i + 2 < 16)                        // issue tile i+2 loads (async)
#pragma unroll
        for (int rep = 0; rep < 4; rep++)
          va[rep] = *(const float4*)(sp + (size_t)(rep * 16 + r) * D + (i + 2) * 64);
      __syncthreads();                       // tile i+1 ready in LDS
      {
        int n0 = (i + 1) * 64;
#pragma unroll
        for (int rep = 0; rep < 4; rep++) {
          int lr = rep * 16 + r;
          ushort4 o;
          o.x = tile[c * 4 + 0][lr];
          o.y = tile[c * 4 + 1][lr];
          o.z = tile[c * 4 + 2][lr];
          o.w = tile[c * 4 + 3][lr];
          *(ushort4*)(dst + (size_t)(n0 + lr) * D + k0 + c * 4) = o;
        }
      }
    }
    return;
  }
  tm -= NTRF;
  if (tm >= meta[0]) return;

  int e = meta[16 + tm], r0 = meta[96 + tm], rend = meta[176 + tm];
  int n0i = blockIdx.x * 128;
  int lane = tid & 63, wid = tid >> 6;
  int wm = wid >> 1, wn = wid & 1;

  const char* gX = (const char*)Xbf;
  const char* gB = (const char*)(W13t + (size_t)e * 2048 * D);

  int prow = tid >> 3, pslot = tid & 7;
  size_t arow[4];
  int brow[4], phys[4];
#pragma unroll
  for (int i = 0; i < 4; i++) {
    int row = i * 32 + prow;
    int gr = r0 + row; if (gr > N_SLOTS - 1) gr = N_SLOTS - 1;
    arow[i] = (size_t)tok[gr] * 2048;
    brow[i] = n0i + row;
    phys[i] = (pslot ^ (row & 7)) * 16;
  }

  f32x4 acc[4][4] = {};

  for (int kt = 0; kt < NKT; kt++) {
    int kb = kt * 128;
#pragma unroll
    for (int i = 0; i < 4; i++) {
      gload_lds16(gX + arow[i] + kb + phys[i], (char*)sA + (i * 256 + tid) * 16);
      gload_lds16(gB + (size_t)brow[i] * 2048 + kb + phys[i],
                  (char*)sB + (i * 256 + tid) * 16);
    }
    __syncthreads();   // vmcnt(0) drain + barrier: tile ready
#pragma unroll
    for (int kk = 0; kk < 2; kk++) {
      int s = kk * 4 + (lane >> 4);
      bf16x8 a[4], b[4];
#pragma unroll
      for (int mf = 0; mf < 4; mf++)
        a[mf] = lds_frag(sA, wm * 64 + mf * 16 + (lane & 15), s);
#pragma unroll
      for (int nf = 0; nf < 4; nf++)
        b[nf] = lds_frag(sB, wn * 64 + nf * 16 + (lane & 15), s);
#pragma unroll
      for (int mf = 0; mf < 4; mf++)
#pragma unroll
        for (int nf = 0; nf < 4; nf++)
          acc[mf][nf] = __builtin_amdgcn_mfma_f32_16x16x32_bf16(a[mf], b[nf], acc[mf][nf], 0, 0, 0);
    }
    __syncthreads();   // all reads done; LDS free for next stage
  }

  // epilogue: nf pairs (W1,W3) -> silu(g)*u
  int cb = (n0i >> 1) + wn * 32 + (lane & 15);
#pragma unroll
  for (int mf = 0; mf < 4; mf++)
#pragma unroll
    for (int v = 0; v < 4; v++) {
      int r = r0 + wm * 64 + mf * 16 + (lane >> 4) * 4 + v;
      if (r >= rend) continue;
#pragma unroll
      for (int p = 0; p < 2; p++) {
        float g = acc[mf][2 * p][v], u = acc[mf][2 * p + 1][v];
        float hv = g / (1.f + __expf(-g)) * u;
        H[(size_t)r * D + cb + p * 16] = f2bf(hv);
      }
    }
}

// ---- GEMM2: tile 128(M) x 128(N), BK=64, 4 waves 2x2, wave 64x64,
// single-buffered (32 KB, 4-5 blocks/CU). T1 XCD-chunked remap (640 works,
// 640%8==0, chunk 80): expert-major chunks keep each XCD's W2t panels
// L2-resident (measured ~-6 us in R8). Writes RAW per-slot rows Y. ----
__global__ __launch_bounds__(256, 4) void gemm2_k(
    const ushort* __restrict__ Hm, const ushort* __restrict__ W2t,
    ushort* __restrict__ Y, const int* __restrict__ meta) {
  __shared__ ushort sA[128 * 64];
  __shared__ ushort sB[128 * 64];
  int flat = blockIdx.y * 8 + blockIdx.x;      // 0..639; HW XCD ~ flat&7
  int work = (flat & 7) * 80 + (flat >> 3);    // XCD c owns works [c*80,(c+1)*80)
  int tm = work >> 3, wnb = work & 7;
  if (tm >= meta[0]) return;
  int e = meta[16 + tm], r0 = meta[96 + tm], rend = meta[176 + tm];
  int n0 = wnb * 128;
  int tid = threadIdx.x, lane = tid & 63, wid = tid >> 6;
  int wm = wid >> 1, wn = wid & 1;

  const char* gH = (const char*)Hm;
  const char* gB = (const char*)(W2t + (size_t)e * D * D);

  int prow = tid >> 3, pslot = tid & 7;
  size_t arow[4];
  int brow[4], phys[4];
#pragma unroll
  for (int i = 0; i < 4; i++) {
    int row = i * 32 + prow;
    int gr = r0 + row; if (gr > N_SLOTS - 1) gr = N_SLOTS - 1;
    arow[i] = (size_t)gr * 2048;
    brow[i] = n0 + row;
    phys[i] = (pslot ^ (row & 7)) * 16;
  }

  f32x4 acc[4][4] = {};

  for (int kt = 0; kt < NKT; kt++) {
    int kb = kt * 128;
#pragma unroll
    for (int i = 0; i < 4; i++) {
      gload_lds16(gH + arow[i] + kb + phys[i], (char*)sA + (i * 256 + tid) * 16);
      gload_lds16(gB + (size_t)brow[i] * 2048 + kb + phys[i],
                  (char*)sB + (i * 256 + tid) * 16);
    }
    __syncthreads();
#pragma unroll
    for (int kk = 0; kk < 2; kk++) {
      int s = kk * 4 + (lane >> 4);
      bf16x8 a[4], b[4];
#pragma unroll
      for (int mf = 0; mf < 4; mf++)
        a[mf] = lds_frag(sA, wm * 64 + mf * 16 + (lane & 15), s);
#pragma unroll
      for (int nf = 0; nf < 4; nf++)
        b[nf] = lds_frag(sB, wn * 64 + nf * 16 + (lane & 15), s);
#pragma unroll
      for (int mf = 0; mf < 4; mf++)
#pragma unroll
        for (int nf = 0; nf < 4; nf++)
          acc[mf][nf] = __builtin_amdgcn_mfma_f32_16x16x32_bf16(a[mf], b[nf], acc[mf][nf], 0, 0, 0);
    }
    __syncthreads();
  }

#pragma unroll
  for (int mf = 0; mf < 4; mf++)
#pragma unroll
    for (int v = 0; v < 4; v++) {
      int r = r0 + wm * 64 + mf * 16 + (lane >> 4) * 4 + v;
      if (r >= rend) continue;
#pragma unroll
      for (int nf = 0; nf < 4; nf++)
        Y[(size_t)r * D + n0 + wn * 64 + nf * 16 + (lane & 15)] = f2bf(acc[mf][nf][v]);
    }
}

// ---- combine: out[t] = ew[2t]*Y[smap[2t]] + ew[2t+1]*Y[smap[2t+1]] ----
__global__ void combine_k(const ushort* __restrict__ Y, const int* __restrict__ smap,
                          const float* __restrict__ ew, float* __restrict__ out) {
  int tkn = blockIdx.x * 4 + (threadIdx.x >> 6);
  int lane = threadIdx.x & 63;
  int p0 = smap[2 * tkn], p1 = smap[2 * tkn + 1];
  float w0 = ew[2 * tkn], w1 = ew[2 * tkn + 1];
  const ushort4* y0 = (const ushort4*)(Y + (size_t)p0 * D);
  const ushort4* y1 = (const ushort4*)(Y + (size_t)p1 * D);
  float4* o = (float4*)(out + (size_t)tkn * D);
#pragma unroll
  for (int j = 0; j < 4; j++) {
    int c = j * 64 + lane;
    ushort4 a = y0[c], b = y1[c];
    float4 v;
    v.x = w0 * bf2f(a.x) + w1 * bf2f(b.x);
    v.y = w0 * bf2f(a.y) + w1 * bf2f(b.y);
    v.z = w0 * bf2f(a.z) + w1 * bf2f(b.z);
    v.w = w0 * bf2f(a.w) + w1 * bf2f(b.w);
    o[c] = v;
  }
}

extern "C" void kernel_launch(void* const* d_in, const int* in_sizes, int n_in,
                              void* d_out, int out_size, void* d_ws, size_t ws_size,
                              hipStream_t stream) {
  const float* x  = (const float*)d_in[0];
  const float* ew = (const float*)d_in[1];
  const int*   ei = (const int*)d_in[2];
  const float* w1 = (const float*)d_in[3];
  const float* w3 = (const float*)d_in[4];
  const float* w2 = (const float*)d_in[5];
  float* out = (float*)d_out;

  char* ws = (char*)d_ws;
  int*    meta = (int*)ws;                            // 4 KB
  int*    tok  = (int*)(ws + 4096);                   // 32 KB
  int*    smap = (int*)(ws + 4096 + 32768);           // 32 KB
  ushort* Xbf  = (ushort*)(ws + (1ull << 20));        // [1,9) MB (token order)
  ushort* W13t = (ushort*)(ws + (9ull << 20));        // [9,41) MB (interleaved)
  ushort* W2t  = (ushort*)(ws + (41ull << 20));       // [41,57) MB (by gemm1 front)
  ushort* Hm   = (ushort*)(ws + (57ull << 20));       // [57,73) MB (slot order)
  // Y overlays Xbf + W13t head: both dead once gemm1 completes (stream order)
  ushort* Ym   = (ushort*)(ws + (1ull << 20));        // [1,17) MB

  prep_k<<<4353, 256, 0, stream>>>(x, ei, ew, w1, w3,
                                   out + (size_t)N_TOKENS * D, meta, tok, smap,
                                   Xbf, W13t);
  gemm1_k<<<dim3(16, NTRF + MAXT), 256, 0, stream>>>(Xbf, W13t, Hm, tok, meta, w2, W2t);
  gemm2_k<<<dim3(8, MAXT), 256, 0, stream>>>(Hm, W2t, Ym, meta);
  combine_k<<<N_TOKENS / 4, 256, 0, stream>>>(Ym, smap, ew, out);
}